// Round 18
// baseline (420.640 us; speedup 1.0000x reference)
//
#include <hip/hip_runtime.h>
#include <cmath>

namespace {
constexpr int TT = 100;
constexpr int B = 512;
constexpr int NIN = 512;
constexpr int NOUT = 512;
constexpr int NEURONS = B * NOUT;  // 262144
constexpr int K3B = 3 * NIN;       // 1536 i8 per A row (3 digit planes)
// Fragment-chunk geometry: chunk = 16 rows x 64 k-bytes = 1024B.
// Intra-chunk granule [fq][fr]: loc = fq*256 + fr*16 (conflict-free ds_read).
// A layout: [rt][p][c][g]*1024, B layout: [nt][c][g]*1024 (nt = 128-col panel).
// v9: block tile 128x256 (B spans 2 panels), BK=64, 24 steps, 48KB LDS.

constexpr double D_I0 = 1e-3;
constexpr double D_KAPPA = (0.75 + 0.66) / 2.0;
constexpr double D_UT = 25.0e-3;
constexpr float F_I0 = (float)D_I0;
constexpr float F_TAU_AMPA = (float)(2e-3 * D_UT / (D_KAPPA * 20.0 * D_I0));
constexpr float F_TAU_GABA = (float)(2e-3 * D_UT / (D_KAPPA * 5.0 * D_I0));
constexpr float F_TAU_SOMA = (float)(2e-3 * D_UT / (D_KAPPA * 5.0 * D_I0));
constexpr float F_TAU_AHP  = (float)(4e-3 * D_UT / (D_KAPPA * 2.0 * D_I0));
constexpr float F_DPI_TAU  = (float)(5.0 * D_I0);
constexpr float F_RESET    = (float)(1.2 * D_I0);
constexpr float F_VR       = (float)(5.0 * D_I0 + D_I0);
constexpr float F_TH       = (float)(2000.0 * D_I0);
constexpr float F_PFB_TH   = (float)(1000.0 * D_I0);
constexpr float F_ALPHA    = 4.0f;
constexpr float F_AMPA_GAIN = (float)(4.0 * 100.0 * D_I0);
constexpr float F_GABA_GAIN = (float)(4.0 * 100.0 * D_I0);
constexpr float F_AHP_GAIN  = (float)(4.0 * 2.0 * D_I0);
constexpr float F_AHP_JUMP  = (float)(4.0 * D_I0);
constexpr float F_PFB_NORM  = (float)(20.0 * D_I0);
constexpr float F_PFB_GAIN  = (float)(100.0 * D_I0);
constexpr float F_ALPHA_DPI = (float)(4.0 * (5.0 * D_I0));
constexpr float F_DT = 1e-3f;
constexpr float F_INIT_MEM = (float)(1.1 * D_I0);
constexpr float F_INV223 = 1.1920928955078125e-7f;  // 2^-23
constexpr unsigned BIAS_MUL = (1u << 14) + (1u << 22);
}  // namespace

typedef __attribute__((ext_vector_type(4))) int i32x4;

__device__ __forceinline__ void gload_lds16(const void* g, void* l) {
  __builtin_amdgcn_global_load_lds(
      (const __attribute__((address_space(1))) void*)g,
      (__attribute__((address_space(3))) void*)l, 16, 0, 0);
}

// Chunked WT (granule [fq][fr]): byte w[k][n] ->
// [n>>7]*65536 + (k8>>3)*8192 + ((n>>4)&7)*1024 + ((k8&7)>>1)*256 + (n&15)*16 + (k8&1)*8.
__global__ __launch_bounds__(256) void build_wt(
    const float* __restrict__ Wa, const float* __restrict__ Wg,
    unsigned char* __restrict__ WTa, unsigned char* __restrict__ WTg) {
  const int t = blockIdx.x * 256 + threadIdx.x;  // 65536 threads
  const float* W = (t >> 15) ? Wg : Wa;
  unsigned char* O = (t >> 15) ? WTg : WTa;
  const int r = t & 32767;
  const int n = r >> 6, k8 = r & 63;
  unsigned char b[8];
#pragma unroll
  for (int j = 0; j < 8; ++j)
    b[j] = (unsigned char)(int)rintf(W[(size_t)(k8 * 8 + j) * 512 + n]);
  const size_t addr = (size_t)(n >> 7) * 65536 + (k8 >> 3) * 8192 +
                      ((n >> 4) & 7) * 1024 +
                      ((k8 & 7) >> 1) * 256 + (n & 15) * 16 + (k8 & 1) * 8;
  *(unsigned long long*)(O + addr) = *(unsigned long long*)b;
}

// colsum[z*512+n] = sum_k rint(W_z[k][n]); runs once.
__global__ __launch_bounds__(256) void colsum_w(
    const float* __restrict__ Wa, const float* __restrict__ Wg,
    int* __restrict__ colsum) {
  const int t = blockIdx.x * 256 + threadIdx.x;  // 1024 threads
  const int z = t >> 9, n = t & 511;
  const float* W = z ? Wg : Wa;
  int s = 0;
  for (int k = 0; k < 512; ++k) s += (int)rintf(W[(size_t)k * 512 + n]);
  colsum[t] = s;
}

// split3 (granule [fq][fr]): in-chunk loc = q*256 + rl*16.
// k = rint(x*2^23); p0=k&127, p1=((k>>7)&255)-128, p2=((k>>15)&255)-128.
__global__ __launch_bounds__(256) void split3(
    const float* __restrict__ XA, const float* __restrict__ XG,
    unsigned char* __restrict__ A4a, unsigned char* __restrict__ A4g, int nwpi) {
  const int wid = (blockIdx.x * 256 + threadIdx.x) >> 6;
  const int l = threadIdx.x & 63;
  const float* X = XA;
  unsigned char* O = A4a;
  int w = wid;
  if (w >= nwpi) { X = XG; O = A4g; w -= nwpi; }
  const int rt = w >> 6, rem = w & 63, c = rem >> 3, g = rem & 7;
  const int rl = l >> 2, q = l & 3;
  const float* src = X + (size_t)(rt * 128 + g * 16 + rl) * 512 + c * 64 + q * 16;
  float a[16];
#pragma unroll
  for (int j = 0; j < 4; ++j) {
    const float4 v = *(const float4*)(src + j * 4);
    a[j * 4 + 0] = v.x; a[j * 4 + 1] = v.y; a[j * 4 + 2] = v.z; a[j * 4 + 3] = v.w;
  }
  unsigned int k[16];
#pragma unroll
  for (int e = 0; e < 16; ++e) k[e] = (unsigned int)rintf(a[e] * 8388608.0f);
  unsigned char* base = O + (size_t)rt * 196608 + c * 8192 + g * 1024 + q * 256 + rl * 16;
  unsigned int u[4];
#pragma unroll
  for (int j = 0; j < 4; ++j)
    u[j] = (k[4 * j] & 127u) | ((k[4 * j + 1] & 127u) << 8) |
           ((k[4 * j + 2] & 127u) << 16) | ((k[4 * j + 3] & 127u) << 24);
  *(uint4*)(base) = make_uint4(u[0], u[1], u[2], u[3]);
#pragma unroll
  for (int j = 0; j < 4; ++j)
    u[j] = (((k[4 * j] >> 7) - 128u) & 255u) | ((((k[4 * j + 1] >> 7) - 128u) & 255u) << 8) |
           ((((k[4 * j + 2] >> 7) - 128u) & 255u) << 16) | ((((k[4 * j + 3] >> 7) - 128u) & 255u) << 24);
  *(uint4*)(base + 65536) = make_uint4(u[0], u[1], u[2], u[3]);
#pragma unroll
  for (int j = 0; j < 4; ++j)
    u[j] = (((k[4 * j] >> 15) - 128u) & 255u) | ((((k[4 * j + 1] >> 15) - 128u) & 255u) << 8) |
           ((((k[4 * j + 2] >> 15) - 128u) & 255u) << 16) | ((((k[4 * j + 3] >> 15) - 128u) & 255u) << 24);
  *(uint4*)(base + 131072) = make_uint4(u[0], u[1], u[2], u[3]);
}

// Exact GEMM v9: block tile 128x256 (4 waves, 64x128 each: fm=4, fn=8), BK=64,
// 24 steps, dbuf'd LDS (A 2x8KB + B 2x16KB = 48KB -> 2 blocks/CU). Staged
// bytes/step per block = 24KB for 2x the output of v7 (-25% total staging,
// the measured co-limiter). Single barrier per step (v6-verified).
// INC = RN((digits @ W Horner) + bias) * 2^-23 — bit-identical to rounds 5-17.
__global__ __launch_bounds__(256) void gemm_i8_v9(
    const unsigned char* __restrict__ A4a, const unsigned char* __restrict__ A4g,
    const unsigned char* __restrict__ WTa, const unsigned char* __restrict__ WTg,
    const int* __restrict__ colsum,
    float* __restrict__ INCa, float* __restrict__ INCg, int nwg) {
  __shared__ __align__(16) unsigned char LDS[49152];
  unsigned char* Al = LDS;           // 2 x 8KB A dbuf
  unsigned char* Bl = LDS + 16384;   // 2 x 16KB B dbuf
  // m-major chunked bijective XCD swizzle: the 4 (n,z) blocks of an m-panel
  // land on one XCD -> A panel fetched once, L2/L3-reused x4.
  const int bid = blockIdx.x;
  const int L = (bid & 7) * (nwg >> 3) + (bid >> 3);  // nwg % 8 == 0
  const int m = L >> 2, sub = L & 3;
  const int n = sub & 1, z = sub >> 1;
  const unsigned char* A4 = (z ? A4g : A4a) + (size_t)m * 196608;
  const unsigned char* Bg = (z ? WTg : WTa) + (size_t)n * 131072;  // 2 panels
  float* C = z ? INCg : INCa;

  const int tid = threadIdx.x;
  const int lane = tid & 63, wave = tid >> 6;
  const int wr = wave >> 1, wc = wave & 1;  // 2x2 waves: 64 rows x 128 cols each
  const int fr = lane & 15, fq = lane >> 4;
  const int goff = tid * 16;                 // per-lane global offset (4KB/round)
  const int woff = wave * 1024;              // wave-uniform LDS base offset
  const int floc = fq * 256 + fr * 16;       // conflict-free fragment loc

  // Prologue: stage s=0 (plane 2, c=0) into buf 0: A 8KB + B 16KB.
#pragma unroll
  for (int j = 0; j < 2; ++j)
    gload_lds16(A4 + 131072 + j * 4096 + goff, Al + j * 4096 + woff);
#pragma unroll
  for (int j = 0; j < 4; ++j)
    gload_lds16(Bg + (j >> 1) * 65536 + (j & 1) * 4096 + goff,
                Bl + j * 4096 + woff);

  i32x4 acc[4][8] = {};
  int buf = 0;
#pragma unroll
  for (int s = 0; s < 24; ++s) {
    // Single barrier: stage(s) complete + buf^1 readers done (v6-verified).
    __syncthreads();
    if (s < 23) {     // stage s+1 into the other buffer
      const int s1 = s + 1;
      const int aoff = (2 - (s1 >> 3)) * 65536 + (s1 & 7) * 8192;
      const int boff = (s1 & 7) * 8192;
#pragma unroll
      for (int j = 0; j < 2; ++j)
        gload_lds16(A4 + aoff + j * 4096 + goff,
                    Al + (buf ^ 1) * 8192 + j * 4096 + woff);
#pragma unroll
      for (int j = 0; j < 4; ++j)
        gload_lds16(Bg + (j >> 1) * 65536 + boff + (j & 1) * 4096 + goff,
                    Bl + (buf ^ 1) * 16384 + j * 4096 + woff);
    }
    // Compute current buffer: one MFMA-K-step of 64B, 4x8 fragments.
    {
      i32x4 af[4], bf[8];
#pragma unroll
      for (int fm = 0; fm < 4; ++fm)
        af[fm] = *(const i32x4*)&Al[buf * 8192 + (wr * 4 + fm) * 1024 + floc];
#pragma unroll
      for (int fn = 0; fn < 8; ++fn)
        bf[fn] = *(const i32x4*)&Bl[buf * 16384 + (wc * 8 + fn) * 1024 + floc];
#pragma unroll
      for (int fm = 0; fm < 4; ++fm)
#pragma unroll
        for (int fn = 0; fn < 8; ++fn)
          acc[fm][fn] = __builtin_amdgcn_mfma_i32_16x16x64_i8(
              af[fm], bf[fn], acc[fm][fn], 0, 0, 0);
    }
    if (s == 7) {    // plane-2 done: Horner scale 2^8 (mod 2^32, exact)
#pragma unroll
      for (int fm = 0; fm < 4; ++fm)
#pragma unroll
        for (int fn = 0; fn < 8; ++fn) acc[fm][fn] = acc[fm][fn] << 8;
    }
    if (s == 15) {   // plane-1 done: scale 2^7
#pragma unroll
      for (int fm = 0; fm < 4; ++fm)
#pragma unroll
        for (int fn = 0; fn < 8; ++fn) acc[fm][fn] = acc[fm][fn] << 7;
    }
    buf ^= 1;
  }
  __syncthreads();  // all waves done reading LDS before epilogue overlays it

  // Epilogue: bias + convert; per-wave LDS transpose (16x132 f32 scratch) ->
  // coalesced 512B-row float4 stores (2 rows per j-iter, 32 lanes each).
  // acc: col = lane&15 (+fn*16), row = fq*4+r (+fm*16)  [m89/m91]
  const int crow0 = m * 128 + wr * 64;
  const int ccol0 = n * 256 + wc * 128;
  unsigned bias[8];
#pragma unroll
  for (int fn = 0; fn < 8; ++fn)
    bias[fn] = BIAS_MUL * (unsigned)colsum[z * 512 + ccol0 + fn * 16 + fr];
  float* scratch = (float*)LDS + wave * (16 * 132);
  const int jlane = lane & 31;
  const int jhalf = lane >> 5;  // 0..1
#pragma unroll
  for (int fm = 0; fm < 4; ++fm) {
#pragma unroll
    for (int fn = 0; fn < 8; ++fn)
#pragma unroll
      for (int r = 0; r < 4; ++r) {
        const unsigned tot = (unsigned)acc[fm][fn][r] + bias[fn];
        scratch[(fq * 4 + r) * 132 + fn * 16 + fr] = (float)tot * F_INV223;
      }
#pragma unroll
    for (int j = 0; j < 8; ++j) {
      const int row = j * 2 + jhalf;           // 0..15
      const float4 v = *(const float4*)&scratch[row * 132 + jlane * 4];
      *(float4*)&C[(size_t)(crow0 + fm * 16 + row) * NOUT + ccol0 + jlane * 4] = v;
    }
  }
}

// One thread per neuron; tc timesteps in registers. Matches JAX step() op-for-op.
__global__ __launch_bounds__(256) void neuron_scan(
    const float* __restrict__ inca, const float* __restrict__ incg,
    float* __restrict__ Sout, float* __restrict__ state, int tc, int first) {
  const int idx = blockIdx.x * 256 + threadIdx.x;
  float mem, ampa, gaba, ahp, refr;
  if (first) {
    mem = F_INIT_MEM; ampa = F_I0; gaba = F_I0; ahp = 0.0f; refr = 0.0f;
  } else {
    mem  = state[idx];
    ampa = state[NEURONS + idx];
    gaba = state[2 * NEURONS + idx];
    ahp  = state[3 * NEURONS + idx];
    refr = state[4 * NEURONS + idx];
  }
  for (int t = 0; t < tc; ++t) {
    const float xa = F_AMPA_GAIN * inca[(size_t)t * NEURONS + idx];
    const float xg = F_GABA_GAIN * incg[(size_t)t * NEURONS + idx];
    const float pfb = F_PFB_GAIN / (1.0f + expf(-(mem - F_PFB_TH) / F_PFB_NORM));
    const float dahp = (-F_AHP_GAIN - ahp) / (F_TAU_AHP * (1.0f + F_AHP_GAIN / ahp));
    const float Iin = fmaxf(ampa - gaba + F_I0, F_I0);
    const float Isum = F_VR + ahp - pfb;
    const float dmem = (F_ALPHA * (Iin - Isum) - Isum * mem / F_DPI_TAU)
                     / (F_TAU_SOMA * (1.0f + F_ALPHA_DPI / mem));
    const float dampa = (F_I0 - ampa) / F_TAU_AMPA;
    ampa = ampa + xa;
    const float dgaba = (F_I0 - gaba) / F_TAU_GABA;
    gaba = gaba + xg;
    refr = refr - (refr > 0.0f ? 1.0f : 0.0f);
    mem = mem + F_DT * dmem * (refr <= 0.0f ? 1.0f : 0.0f);
    ahp = ahp + F_DT * dahp;
    ampa = ampa + F_DT * dampa;
    gaba = gaba + F_DT * dgaba;
    const float S = (mem - F_TH) > 0.0f ? 1.0f : 0.0f;
    refr = refr + floorf(S * 5.0f);
    ahp = ahp + F_AHP_JUMP * S;
    mem = F_RESET * S + mem * (1.0f - S);
    mem = fmaxf(mem, F_I0);
    Sout[(size_t)t * NEURONS + idx] = S;
  }
  state[idx] = mem;
  state[NEURONS + idx] = ampa;
  state[2 * NEURONS + idx] = gaba;
  state[3 * NEURONS + idx] = ahp;
  state[4 * NEURONS + idx] = refr;
}

extern "C" void kernel_launch(void* const* d_in, const int* in_sizes, int n_in,
                              void* d_out, int out_size, void* d_ws, size_t ws_size,
                              hipStream_t stream) {
  const float* XA = (const float*)d_in[0];
  const float* XG = (const float*)d_in[1];
  const float* WA = (const float*)d_in[2];
  const float* WG = (const float*)d_in[3];
  float* S = (float*)d_out;

  // tc capped at 20: chunk working set (A4 30MB + INC 80MB + X 84MB + S 21MB)
  // fits the 256MB L3 -> split->gemm->scan intermediate traffic stays on-die.
  int tc = 1;
  const int cands[6] = {20, 10, 5, 4, 2, 1};
  for (int i = 0; i < 6; ++i) {
    const size_t need = 5771264ull + (size_t)cands[i] * 3670016ull;
    if (need <= ws_size) { tc = cands[i]; break; }
  }

  unsigned char* WTa = (unsigned char*)d_ws;
  unsigned char* WTg = WTa + (size_t)NOUT * 512;
  int* colsum = (int*)(WTg + (size_t)NOUT * 512);
  unsigned char* A4a = (unsigned char*)(colsum + 1024);
  unsigned char* A4g = A4a + (size_t)tc * B * K3B;
  float* INCa  = (float*)(A4g + (size_t)tc * B * K3B);
  float* INCg  = INCa + (size_t)tc * NEURONS;
  float* state = INCg + (size_t)tc * NEURONS;

  build_wt<<<256, 256, 0, stream>>>(WA, WG, WTa, WTg);
  colsum_w<<<4, 256, 0, stream>>>(WA, WG, colsum);

  const int nwpi = tc * 256;              // split waves per input
  const int splitBlocks = nwpi / 2;       // 2 inputs, 4 waves/block
  const int nm = tc * B / 128;            // 128-row m-tiles
  const int nwg = nm * 4;                 // x2 n-tiles x2 z
  const int nch = TT / tc;
  for (int c = 0; c < nch; ++c) {
    const size_t inOff = (size_t)c * tc * B * NIN;
    split3<<<splitBlocks, 256, 0, stream>>>(XA + inOff, XG + inOff, A4a, A4g, nwpi);
    gemm_i8_v9<<<nwg, 256, 0, stream>>>(A4a, A4g, WTa, WTg, colsum, INCa, INCg, nwg);
    neuron_scan<<<NEURONS / 256, 256, 0, stream>>>(
        INCa, INCg, S + (size_t)c * tc * NEURONS, state, tc, c == 0 ? 1 : 0);
  }
}

// Round 19
// 412.011 us; speedup vs baseline: 1.0209x; 1.0209x over previous
//
#include <hip/hip_runtime.h>
#include <cmath>

namespace {
constexpr int TT = 100;
constexpr int B = 512;
constexpr int NIN = 512;
constexpr int NOUT = 512;
constexpr int NEURONS = B * NOUT;  // 262144
constexpr int K3B = 3 * NIN;       // 1536 i8 per A row (3 digit planes)
// Fragment-chunk geometry: chunk = 16 rows x 64 k-bytes = 1024B.
// Intra-chunk granule [fq][fr]: loc = fq*256 + fr*16 (conflict-free ds_read).
// A layout: [rt][p][c][g]*1024, B layout: [nt][c][g]*1024 (nt = 128-col panel).
// v9 tile: 128x256 (B spans 2 panels), BK=64, 24 steps, 48KB LDS; tc=100.

constexpr double D_I0 = 1e-3;
constexpr double D_KAPPA = (0.75 + 0.66) / 2.0;
constexpr double D_UT = 25.0e-3;
constexpr float F_I0 = (float)D_I0;
constexpr float F_TAU_AMPA = (float)(2e-3 * D_UT / (D_KAPPA * 20.0 * D_I0));
constexpr float F_TAU_GABA = (float)(2e-3 * D_UT / (D_KAPPA * 5.0 * D_I0));
constexpr float F_TAU_SOMA = (float)(2e-3 * D_UT / (D_KAPPA * 5.0 * D_I0));
constexpr float F_TAU_AHP  = (float)(4e-3 * D_UT / (D_KAPPA * 2.0 * D_I0));
constexpr float F_DPI_TAU  = (float)(5.0 * D_I0);
constexpr float F_RESET    = (float)(1.2 * D_I0);
constexpr float F_VR       = (float)(5.0 * D_I0 + D_I0);
constexpr float F_TH       = (float)(2000.0 * D_I0);
constexpr float F_PFB_TH   = (float)(1000.0 * D_I0);
constexpr float F_ALPHA    = 4.0f;
constexpr float F_AMPA_GAIN = (float)(4.0 * 100.0 * D_I0);
constexpr float F_GABA_GAIN = (float)(4.0 * 100.0 * D_I0);
constexpr float F_AHP_GAIN  = (float)(4.0 * 2.0 * D_I0);
constexpr float F_AHP_JUMP  = (float)(4.0 * D_I0);
constexpr float F_PFB_NORM  = (float)(20.0 * D_I0);
constexpr float F_PFB_GAIN  = (float)(100.0 * D_I0);
constexpr float F_ALPHA_DPI = (float)(4.0 * (5.0 * D_I0));
constexpr float F_DT = 1e-3f;
constexpr float F_INIT_MEM = (float)(1.1 * D_I0);
constexpr float F_INV223 = 1.1920928955078125e-7f;  // 2^-23
constexpr unsigned BIAS_MUL = (1u << 14) + (1u << 22);
}  // namespace

typedef __attribute__((ext_vector_type(4))) int i32x4;

__device__ __forceinline__ void gload_lds16(const void* g, void* l) {
  __builtin_amdgcn_global_load_lds(
      (const __attribute__((address_space(1))) void*)g,
      (__attribute__((address_space(3))) void*)l, 16, 0, 0);
}

// Chunked WT (granule [fq][fr]): byte w[k][n] ->
// [n>>7]*65536 + (k8>>3)*8192 + ((n>>4)&7)*1024 + ((k8&7)>>1)*256 + (n&15)*16 + (k8&1)*8.
__global__ __launch_bounds__(256) void build_wt(
    const float* __restrict__ Wa, const float* __restrict__ Wg,
    unsigned char* __restrict__ WTa, unsigned char* __restrict__ WTg) {
  const int t = blockIdx.x * 256 + threadIdx.x;  // 65536 threads
  const float* W = (t >> 15) ? Wg : Wa;
  unsigned char* O = (t >> 15) ? WTg : WTa;
  const int r = t & 32767;
  const int n = r >> 6, k8 = r & 63;
  unsigned char b[8];
#pragma unroll
  for (int j = 0; j < 8; ++j)
    b[j] = (unsigned char)(int)rintf(W[(size_t)(k8 * 8 + j) * 512 + n]);
  const size_t addr = (size_t)(n >> 7) * 65536 + (k8 >> 3) * 8192 +
                      ((n >> 4) & 7) * 1024 +
                      ((k8 & 7) >> 1) * 256 + (n & 15) * 16 + (k8 & 1) * 8;
  *(unsigned long long*)(O + addr) = *(unsigned long long*)b;
}

// colsum[z*512+n] = sum_k rint(W_z[k][n]); runs once.
__global__ __launch_bounds__(256) void colsum_w(
    const float* __restrict__ Wa, const float* __restrict__ Wg,
    int* __restrict__ colsum) {
  const int t = blockIdx.x * 256 + threadIdx.x;  // 1024 threads
  const int z = t >> 9, n = t & 511;
  const float* W = z ? Wg : Wa;
  int s = 0;
  for (int k = 0; k < 512; ++k) s += (int)rintf(W[(size_t)k * 512 + n]);
  colsum[t] = s;
}

// split3 (granule [fq][fr]): in-chunk loc = q*256 + rl*16.
// k = rint(x*2^23); p0=k&127, p1=((k>>7)&255)-128, p2=((k>>15)&255)-128.
__global__ __launch_bounds__(256) void split3(
    const float* __restrict__ XA, const float* __restrict__ XG,
    unsigned char* __restrict__ A4a, unsigned char* __restrict__ A4g, int nwpi) {
  const int wid = (blockIdx.x * 256 + threadIdx.x) >> 6;
  const int l = threadIdx.x & 63;
  const float* X = XA;
  unsigned char* O = A4a;
  int w = wid;
  if (w >= nwpi) { X = XG; O = A4g; w -= nwpi; }
  const int rt = w >> 6, rem = w & 63, c = rem >> 3, g = rem & 7;
  const int rl = l >> 2, q = l & 3;
  const float* src = X + (size_t)(rt * 128 + g * 16 + rl) * 512 + c * 64 + q * 16;
  float a[16];
#pragma unroll
  for (int j = 0; j < 4; ++j) {
    const float4 v = *(const float4*)(src + j * 4);
    a[j * 4 + 0] = v.x; a[j * 4 + 1] = v.y; a[j * 4 + 2] = v.z; a[j * 4 + 3] = v.w;
  }
  unsigned int k[16];
#pragma unroll
  for (int e = 0; e < 16; ++e) k[e] = (unsigned int)rintf(a[e] * 8388608.0f);
  unsigned char* base = O + (size_t)rt * 196608 + c * 8192 + g * 1024 + q * 256 + rl * 16;
  unsigned int u[4];
#pragma unroll
  for (int j = 0; j < 4; ++j)
    u[j] = (k[4 * j] & 127u) | ((k[4 * j + 1] & 127u) << 8) |
           ((k[4 * j + 2] & 127u) << 16) | ((k[4 * j + 3] & 127u) << 24);
  *(uint4*)(base) = make_uint4(u[0], u[1], u[2], u[3]);
#pragma unroll
  for (int j = 0; j < 4; ++j)
    u[j] = (((k[4 * j] >> 7) - 128u) & 255u) | ((((k[4 * j + 1] >> 7) - 128u) & 255u) << 8) |
           ((((k[4 * j + 2] >> 7) - 128u) & 255u) << 16) | ((((k[4 * j + 3] >> 7) - 128u) & 255u) << 24);
  *(uint4*)(base + 65536) = make_uint4(u[0], u[1], u[2], u[3]);
#pragma unroll
  for (int j = 0; j < 4; ++j)
    u[j] = (((k[4 * j] >> 15) - 128u) & 255u) | ((((k[4 * j + 1] >> 15) - 128u) & 255u) << 8) |
           ((((k[4 * j + 2] >> 15) - 128u) & 255u) << 16) | ((((k[4 * j + 3] >> 15) - 128u) & 255u) << 24);
  *(uint4*)(base + 131072) = make_uint4(u[0], u[1], u[2], u[3]);
}

// Exact GEMM v9 (tile verified @tc=20 in R18): 128x256 block tile (4 waves,
// 64x128 each), BK=64, 24 steps, dbuf LDS 48KB, single barrier/step.
// INC = RN((digits @ W Horner) + bias) * 2^-23 — bit-identical to rounds 5-18.
__global__ __launch_bounds__(256) void gemm_i8_v9(
    const unsigned char* __restrict__ A4a, const unsigned char* __restrict__ A4g,
    const unsigned char* __restrict__ WTa, const unsigned char* __restrict__ WTg,
    const int* __restrict__ colsum,
    float* __restrict__ INCa, float* __restrict__ INCg, int nwg) {
  __shared__ __align__(16) unsigned char LDS[49152];
  unsigned char* Al = LDS;           // 2 x 8KB A dbuf
  unsigned char* Bl = LDS + 16384;   // 2 x 16KB B dbuf
  const int bid = blockIdx.x;
  const int L = (bid & 7) * (nwg >> 3) + (bid >> 3);  // nwg % 8 == 0
  const int m = L >> 2, sub = L & 3;
  const int n = sub & 1, z = sub >> 1;
  const unsigned char* A4 = (z ? A4g : A4a) + (size_t)m * 196608;
  const unsigned char* Bg = (z ? WTg : WTa) + (size_t)n * 131072;  // 2 panels
  float* C = z ? INCg : INCa;

  const int tid = threadIdx.x;
  const int lane = tid & 63, wave = tid >> 6;
  const int wr = wave >> 1, wc = wave & 1;  // 2x2 waves: 64 rows x 128 cols each
  const int fr = lane & 15, fq = lane >> 4;
  const int goff = tid * 16;
  const int woff = wave * 1024;
  const int floc = fq * 256 + fr * 16;

  // Prologue: stage s=0 (plane 2, c=0) into buf 0: A 8KB + B 16KB.
#pragma unroll
  for (int j = 0; j < 2; ++j)
    gload_lds16(A4 + 131072 + j * 4096 + goff, Al + j * 4096 + woff);
#pragma unroll
  for (int j = 0; j < 4; ++j)
    gload_lds16(Bg + (j >> 1) * 65536 + (j & 1) * 4096 + goff,
                Bl + j * 4096 + woff);

  i32x4 acc[4][8] = {};
  int buf = 0;
#pragma unroll
  for (int s = 0; s < 24; ++s) {
    __syncthreads();  // stage(s) complete + buf^1 readers done (v6-verified)
    if (s < 23) {
      const int s1 = s + 1;
      const int aoff = (2 - (s1 >> 3)) * 65536 + (s1 & 7) * 8192;
      const int boff = (s1 & 7) * 8192;
#pragma unroll
      for (int j = 0; j < 2; ++j)
        gload_lds16(A4 + aoff + j * 4096 + goff,
                    Al + (buf ^ 1) * 8192 + j * 4096 + woff);
#pragma unroll
      for (int j = 0; j < 4; ++j)
        gload_lds16(Bg + (j >> 1) * 65536 + boff + (j & 1) * 4096 + goff,
                    Bl + (buf ^ 1) * 16384 + j * 4096 + woff);
    }
    {
      i32x4 af[4], bf[8];
#pragma unroll
      for (int fm = 0; fm < 4; ++fm)
        af[fm] = *(const i32x4*)&Al[buf * 8192 + (wr * 4 + fm) * 1024 + floc];
#pragma unroll
      for (int fn = 0; fn < 8; ++fn)
        bf[fn] = *(const i32x4*)&Bl[buf * 16384 + (wc * 8 + fn) * 1024 + floc];
#pragma unroll
      for (int fm = 0; fm < 4; ++fm)
#pragma unroll
        for (int fn = 0; fn < 8; ++fn)
          acc[fm][fn] = __builtin_amdgcn_mfma_i32_16x16x64_i8(
              af[fm], bf[fn], acc[fm][fn], 0, 0, 0);
    }
    if (s == 7) {    // plane-2 done: Horner scale 2^8 (mod 2^32, exact)
#pragma unroll
      for (int fm = 0; fm < 4; ++fm)
#pragma unroll
        for (int fn = 0; fn < 8; ++fn) acc[fm][fn] = acc[fm][fn] << 8;
    }
    if (s == 15) {   // plane-1 done: scale 2^7
#pragma unroll
      for (int fm = 0; fm < 4; ++fm)
#pragma unroll
        for (int fn = 0; fn < 8; ++fn) acc[fm][fn] = acc[fm][fn] << 7;
    }
    buf ^= 1;
  }
  __syncthreads();  // all waves done reading LDS before epilogue overlays it

  // Epilogue: bias + convert; per-wave LDS transpose (16x132 f32 scratch) ->
  // coalesced 512B-row float4 stores. acc: col=lane&15 (+fn*16), row=fq*4+r (+fm*16).
  const int crow0 = m * 128 + wr * 64;
  const int ccol0 = n * 256 + wc * 128;
  unsigned bias[8];
#pragma unroll
  for (int fn = 0; fn < 8; ++fn)
    bias[fn] = BIAS_MUL * (unsigned)colsum[z * 512 + ccol0 + fn * 16 + fr];
  float* scratch = (float*)LDS + wave * (16 * 132);
  const int jlane = lane & 31;
  const int jhalf = lane >> 5;
#pragma unroll
  for (int fm = 0; fm < 4; ++fm) {
#pragma unroll
    for (int fn = 0; fn < 8; ++fn)
#pragma unroll
      for (int r = 0; r < 4; ++r) {
        const unsigned tot = (unsigned)acc[fm][fn][r] + bias[fn];
        scratch[(fq * 4 + r) * 132 + fn * 16 + fr] = (float)tot * F_INV223;
      }
#pragma unroll
    for (int j = 0; j < 8; ++j) {
      const int row = j * 2 + jhalf;
      const float4 v = *(const float4*)&scratch[row * 132 + jlane * 4];
      *(float4*)&C[(size_t)(crow0 + fm * 16 + row) * NOUT + ccol0 + jlane * 4] = v;
    }
  }
}

// One thread per neuron; tc timesteps in registers. Matches JAX step() op-for-op.
__global__ __launch_bounds__(256) void neuron_scan(
    const float* __restrict__ inca, const float* __restrict__ incg,
    float* __restrict__ Sout, float* __restrict__ state, int tc, int first) {
  const int idx = blockIdx.x * 256 + threadIdx.x;
  float mem, ampa, gaba, ahp, refr;
  if (first) {
    mem = F_INIT_MEM; ampa = F_I0; gaba = F_I0; ahp = 0.0f; refr = 0.0f;
  } else {
    mem  = state[idx];
    ampa = state[NEURONS + idx];
    gaba = state[2 * NEURONS + idx];
    ahp  = state[3 * NEURONS + idx];
    refr = state[4 * NEURONS + idx];
  }
  for (int t = 0; t < tc; ++t) {
    const float xa = F_AMPA_GAIN * inca[(size_t)t * NEURONS + idx];
    const float xg = F_GABA_GAIN * incg[(size_t)t * NEURONS + idx];
    const float pfb = F_PFB_GAIN / (1.0f + expf(-(mem - F_PFB_TH) / F_PFB_NORM));
    const float dahp = (-F_AHP_GAIN - ahp) / (F_TAU_AHP * (1.0f + F_AHP_GAIN / ahp));
    const float Iin = fmaxf(ampa - gaba + F_I0, F_I0);
    const float Isum = F_VR + ahp - pfb;
    const float dmem = (F_ALPHA * (Iin - Isum) - Isum * mem / F_DPI_TAU)
                     / (F_TAU_SOMA * (1.0f + F_ALPHA_DPI / mem));
    const float dampa = (F_I0 - ampa) / F_TAU_AMPA;
    ampa = ampa + xa;
    const float dgaba = (F_I0 - gaba) / F_TAU_GABA;
    gaba = gaba + xg;
    refr = refr - (refr > 0.0f ? 1.0f : 0.0f);
    mem = mem + F_DT * dmem * (refr <= 0.0f ? 1.0f : 0.0f);
    ahp = ahp + F_DT * dahp;
    ampa = ampa + F_DT * dampa;
    gaba = gaba + F_DT * dgaba;
    const float S = (mem - F_TH) > 0.0f ? 1.0f : 0.0f;
    refr = refr + floorf(S * 5.0f);
    ahp = ahp + F_AHP_JUMP * S;
    mem = F_RESET * S + mem * (1.0f - S);
    mem = fmaxf(mem, F_I0);
    Sout[(size_t)t * NEURONS + idx] = S;
  }
  state[idx] = mem;
  state[NEURONS + idx] = ampa;
  state[2 * NEURONS + idx] = gaba;
  state[3 * NEURONS + idx] = ahp;
  state[4 * NEURONS + idx] = refr;
}

extern "C" void kernel_launch(void* const* d_in, const int* in_sizes, int n_in,
                              void* d_out, int out_size, void* d_ws, size_t ws_size,
                              hipStream_t stream) {
  const float* XA = (const float*)d_in[0];
  const float* XG = (const float*)d_in[1];
  const float* WA = (const float*)d_in[2];
  const float* WG = (const float*)d_in[3];
  float* S = (float*)d_out;

  // tc=100 (R18 lesson: tc=20 gives only 320-block gemm grids = half-idle CUs).
  int tc = 1;
  const int cands[8] = {100, 50, 25, 20, 10, 5, 2, 1};
  for (int i = 0; i < 8; ++i) {
    const size_t need = 5771264ull + (size_t)cands[i] * 3670016ull;
    if (need <= ws_size) { tc = cands[i]; break; }
  }

  unsigned char* WTa = (unsigned char*)d_ws;
  unsigned char* WTg = WTa + (size_t)NOUT * 512;
  int* colsum = (int*)(WTg + (size_t)NOUT * 512);
  unsigned char* A4a = (unsigned char*)(colsum + 1024);
  unsigned char* A4g = A4a + (size_t)tc * B * K3B;
  float* INCa  = (float*)(A4g + (size_t)tc * B * K3B);
  float* INCg  = INCa + (size_t)tc * NEURONS;
  float* state = INCg + (size_t)tc * NEURONS;

  build_wt<<<256, 256, 0, stream>>>(WA, WG, WTa, WTg);
  colsum_w<<<4, 256, 0, stream>>>(WA, WG, colsum);

  const int nwpi = tc * 256;              // split waves per input
  const int splitBlocks = nwpi / 2;       // 2 inputs, 4 waves/block
  const int nm = tc * B / 128;            // 128-row m-tiles
  const int nwg = nm * 4;                 // x2 n-tiles x2 z
  const int nch = TT / tc;
  for (int c = 0; c < nch; ++c) {
    const size_t inOff = (size_t)c * tc * B * NIN;
    split3<<<splitBlocks, 256, 0, stream>>>(XA + inOff, XG + inOff, A4a, A4g, nwpi);
    gemm_i8_v9<<<nwg, 256, 0, stream>>>(A4a, A4g, WTa, WTg, colsum, INCa, INCg, nwg);
    neuron_scan<<<NEURONS / 256, 256, 0, stream>>>(
        INCa, INCg, S + (size_t)c * tc * NEURONS, state, tc, c == 0 ? 1 : 0);
  }
}

// Round 20
// 348.316 us; speedup vs baseline: 1.2076x; 1.1829x over previous
//
#include <hip/hip_runtime.h>
#include <cmath>

namespace {
constexpr int TT = 100;
constexpr int B = 512;
constexpr int NIN = 512;
constexpr int NOUT = 512;
constexpr int NEURONS = B * NOUT;  // 262144
constexpr int K3B = 3 * NIN;       // 1536 i8 per A row (3 digit planes)
// Fragment-chunk geometry: chunk = 16 rows x 64 k-bytes = 1024B.
// Intra-chunk granule [fq][fr]: loc = fq*256 + fr*16 (conflict-free ds_read).
// A layout: [rt][p][c][g]*1024, B layout: [nt][c][g]*1024.
// v10: 128x128 tile, BK=64, 24 steps, QUAD-buffered LDS (depth-3 prefetch),
// raw s_barrier + counted vmcnt (T3+T4) — loads stay in flight across barriers.

constexpr double D_I0 = 1e-3;
constexpr double D_KAPPA = (0.75 + 0.66) / 2.0;
constexpr double D_UT = 25.0e-3;
constexpr float F_I0 = (float)D_I0;
constexpr float F_TAU_AMPA = (float)(2e-3 * D_UT / (D_KAPPA * 20.0 * D_I0));
constexpr float F_TAU_GABA = (float)(2e-3 * D_UT / (D_KAPPA * 5.0 * D_I0));
constexpr float F_TAU_SOMA = (float)(2e-3 * D_UT / (D_KAPPA * 5.0 * D_I0));
constexpr float F_TAU_AHP  = (float)(4e-3 * D_UT / (D_KAPPA * 2.0 * D_I0));
constexpr float F_DPI_TAU  = (float)(5.0 * D_I0);
constexpr float F_RESET    = (float)(1.2 * D_I0);
constexpr float F_VR       = (float)(5.0 * D_I0 + D_I0);
constexpr float F_TH       = (float)(2000.0 * D_I0);
constexpr float F_PFB_TH   = (float)(1000.0 * D_I0);
constexpr float F_ALPHA    = 4.0f;
constexpr float F_AMPA_GAIN = (float)(4.0 * 100.0 * D_I0);
constexpr float F_GABA_GAIN = (float)(4.0 * 100.0 * D_I0);
constexpr float F_AHP_GAIN  = (float)(4.0 * 2.0 * D_I0);
constexpr float F_AHP_JUMP  = (float)(4.0 * D_I0);
constexpr float F_PFB_NORM  = (float)(20.0 * D_I0);
constexpr float F_PFB_GAIN  = (float)(100.0 * D_I0);
constexpr float F_ALPHA_DPI = (float)(4.0 * (5.0 * D_I0));
constexpr float F_DT = 1e-3f;
constexpr float F_INIT_MEM = (float)(1.1 * D_I0);
constexpr float F_INV223 = 1.1920928955078125e-7f;  // 2^-23
constexpr unsigned BIAS_MUL = (1u << 14) + (1u << 22);
}  // namespace

typedef __attribute__((ext_vector_type(4))) int i32x4;

__device__ __forceinline__ void gload_lds16(const void* g, void* l) {
  __builtin_amdgcn_global_load_lds(
      (const __attribute__((address_space(1))) void*)g,
      (__attribute__((address_space(3))) void*)l, 16, 0, 0);
}

#define WAITVM(N) asm volatile("s_waitcnt vmcnt(" #N ")" ::: "memory")

// Chunked WT (granule [fq][fr]): byte w[k][n] ->
// [n>>7]*65536 + (k8>>3)*8192 + ((n>>4)&7)*1024 + ((k8&7)>>1)*256 + (n&15)*16 + (k8&1)*8.
__global__ __launch_bounds__(256) void build_wt(
    const float* __restrict__ Wa, const float* __restrict__ Wg,
    unsigned char* __restrict__ WTa, unsigned char* __restrict__ WTg) {
  const int t = blockIdx.x * 256 + threadIdx.x;  // 65536 threads
  const float* W = (t >> 15) ? Wg : Wa;
  unsigned char* O = (t >> 15) ? WTg : WTa;
  const int r = t & 32767;
  const int n = r >> 6, k8 = r & 63;
  unsigned char b[8];
#pragma unroll
  for (int j = 0; j < 8; ++j)
    b[j] = (unsigned char)(int)rintf(W[(size_t)(k8 * 8 + j) * 512 + n]);
  const size_t addr = (size_t)(n >> 7) * 65536 + (k8 >> 3) * 8192 +
                      ((n >> 4) & 7) * 1024 +
                      ((k8 & 7) >> 1) * 256 + (n & 15) * 16 + (k8 & 1) * 8;
  *(unsigned long long*)(O + addr) = *(unsigned long long*)b;
}

// colsum[z*512+n] = sum_k rint(W_z[k][n]); runs once.
__global__ __launch_bounds__(256) void colsum_w(
    const float* __restrict__ Wa, const float* __restrict__ Wg,
    int* __restrict__ colsum) {
  const int t = blockIdx.x * 256 + threadIdx.x;  // 1024 threads
  const int z = t >> 9, n = t & 511;
  const float* W = z ? Wg : Wa;
  int s = 0;
  for (int k = 0; k < 512; ++k) s += (int)rintf(W[(size_t)k * 512 + n]);
  colsum[t] = s;
}

// split3 (granule [fq][fr]): in-chunk loc = q*256 + rl*16.
// k = rint(x*2^23); p0=k&127, p1=((k>>7)&255)-128, p2=((k>>15)&255)-128.
__global__ __launch_bounds__(256) void split3(
    const float* __restrict__ XA, const float* __restrict__ XG,
    unsigned char* __restrict__ A4a, unsigned char* __restrict__ A4g, int nwpi) {
  const int wid = (blockIdx.x * 256 + threadIdx.x) >> 6;
  const int l = threadIdx.x & 63;
  const float* X = XA;
  unsigned char* O = A4a;
  int w = wid;
  if (w >= nwpi) { X = XG; O = A4g; w -= nwpi; }
  const int rt = w >> 6, rem = w & 63, c = rem >> 3, g = rem & 7;
  const int rl = l >> 2, q = l & 3;
  const float* src = X + (size_t)(rt * 128 + g * 16 + rl) * 512 + c * 64 + q * 16;
  float a[16];
#pragma unroll
  for (int j = 0; j < 4; ++j) {
    const float4 v = *(const float4*)(src + j * 4);
    a[j * 4 + 0] = v.x; a[j * 4 + 1] = v.y; a[j * 4 + 2] = v.z; a[j * 4 + 3] = v.w;
  }
  unsigned int k[16];
#pragma unroll
  for (int e = 0; e < 16; ++e) k[e] = (unsigned int)rintf(a[e] * 8388608.0f);
  unsigned char* base = O + (size_t)rt * 196608 + c * 8192 + g * 1024 + q * 256 + rl * 16;
  unsigned int u[4];
#pragma unroll
  for (int j = 0; j < 4; ++j)
    u[j] = (k[4 * j] & 127u) | ((k[4 * j + 1] & 127u) << 8) |
           ((k[4 * j + 2] & 127u) << 16) | ((k[4 * j + 3] & 127u) << 24);
  *(uint4*)(base) = make_uint4(u[0], u[1], u[2], u[3]);
#pragma unroll
  for (int j = 0; j < 4; ++j)
    u[j] = (((k[4 * j] >> 7) - 128u) & 255u) | ((((k[4 * j + 1] >> 7) - 128u) & 255u) << 8) |
           ((((k[4 * j + 2] >> 7) - 128u) & 255u) << 16) | ((((k[4 * j + 3] >> 7) - 128u) & 255u) << 24);
  *(uint4*)(base + 65536) = make_uint4(u[0], u[1], u[2], u[3]);
#pragma unroll
  for (int j = 0; j < 4; ++j)
    u[j] = (((k[4 * j] >> 15) - 128u) & 255u) | ((((k[4 * j + 1] >> 15) - 128u) & 255u) << 8) |
           ((((k[4 * j + 2] >> 15) - 128u) & 255u) << 16) | ((((k[4 * j + 3] >> 15) - 128u) & 255u) << 24);
  *(uint4*)(base + 131072) = make_uint4(u[0], u[1], u[2], u[3]);
}

// Exact GEMM v10: v8 geometry + T3/T4 pipeline. Quad-buffered LDS (4x16KB),
// depth-3 prefetch; raw s_barrier + counted vmcnt (never 0 in steady state).
// Per step s: WAITVM(own stage(s) landed) -> s_barrier (all landed; all done
// reading buf[(s-1)&3]) -> issue stage(s+3) -> compute buf[s&3].
// INC = RN((digits @ W Horner) + bias) * 2^-23 — bit-identical to rounds 5-19.
__global__ __launch_bounds__(256) void gemm_i8_v10(
    const unsigned char* __restrict__ A4a, const unsigned char* __restrict__ A4g,
    const unsigned char* __restrict__ WTa, const unsigned char* __restrict__ WTg,
    const int* __restrict__ colsum,
    float* __restrict__ INCa, float* __restrict__ INCg, int nwg) {
  __shared__ __align__(16) unsigned char LDS[65536];
  unsigned char* Al = LDS;           // 4 x 8KB A bufs
  unsigned char* Bl = LDS + 32768;   // 4 x 8KB B bufs
  const int bid = blockIdx.x;
  const int L = (bid & 7) * (nwg >> 3) + (bid >> 3);  // nwg % 8 == 0
  const int m = L >> 3, sub = L & 7;
  const int n = sub & 3, z = sub >> 2;
  const unsigned char* A4 = (z ? A4g : A4a) + (size_t)m * 196608;
  const unsigned char* Bg = (z ? WTg : WTa) + (size_t)n * 65536;
  float* C = z ? INCg : INCa;

  const int tid = threadIdx.x;
  const int lane = tid & 63, wave = tid >> 6;
  const int wr = wave >> 1, wc = wave & 1;  // 2x2 waves: 64x64 out each
  const int fr = lane & 15, fq = lane >> 4;
  const int goff = tid * 16;
  const int woff = wave * 1024;
  const int floc = fq * 256 + fr * 16;

  // stage(t): A/B c-block t&7 of plane 2-(t>>3) into buf t&3 (4 loads/thread).
#define STAGE(t)                                                            \
  {                                                                         \
    const int aoff_ = (2 - ((t) >> 3)) * 65536 + ((t) & 7) * 8192;          \
    const int boff_ = ((t) & 7) * 8192;                                     \
    const int lb_ = ((t) & 3) * 8192 + woff;                                \
    gload_lds16(A4 + aoff_ + goff, Al + lb_);                               \
    gload_lds16(A4 + aoff_ + 4096 + goff, Al + lb_ + 4096);                 \
    gload_lds16(Bg + boff_ + goff, Bl + lb_);                               \
    gload_lds16(Bg + boff_ + 4096 + goff, Bl + lb_ + 4096);                 \
  }

  // Prologue: stages 0,1,2 in flight (12 loads/thread outstanding).
  STAGE(0) STAGE(1) STAGE(2)

  i32x4 acc[4][4] = {};
#pragma unroll
  for (int s = 0; s < 24; ++s) {
    // Own stage(s) landed; stages s+1..s+2 (8 loads) may stay in flight.
    if (s <= 21) WAITVM(8);
    else if (s == 22) WAITVM(4);
    else WAITVM(0);
    __builtin_amdgcn_s_barrier();     // all waves' stage(s) landed; all done
    asm volatile("" ::: "memory");    //   reading buf[(s-1)&3]
    __builtin_amdgcn_sched_barrier(0);
    if (s + 3 < 24) STAGE(s + 3)      // safe: buf[(s+3)&3] readers finished
    {
      const int b = (s & 3) * 8192;
      i32x4 af[4], bf[4];
#pragma unroll
      for (int fm = 0; fm < 4; ++fm)
        af[fm] = *(const i32x4*)&Al[b + (wr * 4 + fm) * 1024 + floc];
#pragma unroll
      for (int fn = 0; fn < 4; ++fn)
        bf[fn] = *(const i32x4*)&Bl[b + (wc * 4 + fn) * 1024 + floc];
#pragma unroll
      for (int fm = 0; fm < 4; ++fm)
#pragma unroll
        for (int fn = 0; fn < 4; ++fn)
          acc[fm][fn] = __builtin_amdgcn_mfma_i32_16x16x64_i8(
              af[fm], bf[fn], acc[fm][fn], 0, 0, 0);
    }
    if (s == 7) {    // plane-2 done: Horner scale 2^8 (mod 2^32, exact)
#pragma unroll
      for (int fm = 0; fm < 4; ++fm)
#pragma unroll
        for (int fn = 0; fn < 4; ++fn) acc[fm][fn] = acc[fm][fn] << 8;
    }
    if (s == 15) {   // plane-1 done: scale 2^7
#pragma unroll
      for (int fm = 0; fm < 4; ++fm)
#pragma unroll
        for (int fn = 0; fn < 4; ++fn) acc[fm][fn] = acc[fm][fn] << 7;
    }
  }
#undef STAGE
  __syncthreads();  // full drain before epilogue overlays LDS

  // Epilogue (R9-verified): bias + convert; per-wave LDS transpose ->
  // coalesced 256B-row dwordx4 stores.
  // acc: col = lane&15 (+fn*16), row = fq*4+r (+fm*16)  [m89/m91]
  const int crow0 = m * 128 + wr * 64;
  const int ccol0 = n * 128 + wc * 64;
  unsigned bias[4];
#pragma unroll
  for (int fn = 0; fn < 4; ++fn)
    bias[fn] = BIAS_MUL * (unsigned)colsum[z * 512 + ccol0 + fn * 16 + fr];
  float* scratch = (float*)LDS + wave * (16 * 68);
  const int erow = lane >> 4;
  const int ecol = (lane & 15) * 4;
#pragma unroll
  for (int fm = 0; fm < 4; ++fm) {
#pragma unroll
    for (int fn = 0; fn < 4; ++fn)
#pragma unroll
      for (int r = 0; r < 4; ++r) {
        const unsigned tot = (unsigned)acc[fm][fn][r] + bias[fn];
        scratch[(fq * 4 + r) * 68 + fn * 16 + fr] = (float)tot * F_INV223;
      }
    float4 rows[4];
#pragma unroll
    for (int j = 0; j < 4; ++j)
      rows[j] = *(const float4*)&scratch[(erow + 4 * j) * 68 + ecol];
#pragma unroll
    for (int j = 0; j < 4; ++j) {
      const int grow = crow0 + fm * 16 + erow + 4 * j;
      *(float4*)&C[(size_t)grow * NOUT + ccol0 + ecol] = rows[j];
    }
  }
}

// One thread per neuron; tc timesteps in registers. Matches JAX step() op-for-op.
__global__ __launch_bounds__(256) void neuron_scan(
    const float* __restrict__ inca, const float* __restrict__ incg,
    float* __restrict__ Sout, float* __restrict__ state, int tc, int first) {
  const int idx = blockIdx.x * 256 + threadIdx.x;
  float mem, ampa, gaba, ahp, refr;
  if (first) {
    mem = F_INIT_MEM; ampa = F_I0; gaba = F_I0; ahp = 0.0f; refr = 0.0f;
  } else {
    mem  = state[idx];
    ampa = state[NEURONS + idx];
    gaba = state[2 * NEURONS + idx];
    ahp  = state[3 * NEURONS + idx];
    refr = state[4 * NEURONS + idx];
  }
  for (int t = 0; t < tc; ++t) {
    const float xa = F_AMPA_GAIN * inca[(size_t)t * NEURONS + idx];
    const float xg = F_GABA_GAIN * incg[(size_t)t * NEURONS + idx];
    const float pfb = F_PFB_GAIN / (1.0f + expf(-(mem - F_PFB_TH) / F_PFB_NORM));
    const float dahp = (-F_AHP_GAIN - ahp) / (F_TAU_AHP * (1.0f + F_AHP_GAIN / ahp));
    const float Iin = fmaxf(ampa - gaba + F_I0, F_I0);
    const float Isum = F_VR + ahp - pfb;
    const float dmem = (F_ALPHA * (Iin - Isum) - Isum * mem / F_DPI_TAU)
                     / (F_TAU_SOMA * (1.0f + F_ALPHA_DPI / mem));
    const float dampa = (F_I0 - ampa) / F_TAU_AMPA;
    ampa = ampa + xa;
    const float dgaba = (F_I0 - gaba) / F_TAU_GABA;
    gaba = gaba + xg;
    refr = refr - (refr > 0.0f ? 1.0f : 0.0f);
    mem = mem + F_DT * dmem * (refr <= 0.0f ? 1.0f : 0.0f);
    ahp = ahp + F_DT * dahp;
    ampa = ampa + F_DT * dampa;
    gaba = gaba + F_DT * dgaba;
    const float S = (mem - F_TH) > 0.0f ? 1.0f : 0.0f;
    refr = refr + floorf(S * 5.0f);
    ahp = ahp + F_AHP_JUMP * S;
    mem = F_RESET * S + mem * (1.0f - S);
    mem = fmaxf(mem, F_I0);
    Sout[(size_t)t * NEURONS + idx] = S;
  }
  state[idx] = mem;
  state[NEURONS + idx] = ampa;
  state[2 * NEURONS + idx] = gaba;
  state[3 * NEURONS + idx] = ahp;
  state[4 * NEURONS + idx] = refr;
}

extern "C" void kernel_launch(void* const* d_in, const int* in_sizes, int n_in,
                              void* d_out, int out_size, void* d_ws, size_t ws_size,
                              hipStream_t stream) {
  const float* XA = (const float*)d_in[0];
  const float* XG = (const float*)d_in[1];
  const float* WA = (const float*)d_in[2];
  const float* WG = (const float*)d_in[3];
  float* S = (float*)d_out;

  int tc = 1;
  const int cands[8] = {100, 50, 25, 20, 10, 5, 2, 1};
  for (int i = 0; i < 8; ++i) {
    const size_t need = 5771264ull + (size_t)cands[i] * 3670016ull;
    if (need <= ws_size) { tc = cands[i]; break; }
  }

  unsigned char* WTa = (unsigned char*)d_ws;
  unsigned char* WTg = WTa + (size_t)NOUT * 512;
  int* colsum = (int*)(WTg + (size_t)NOUT * 512);
  unsigned char* A4a = (unsigned char*)(colsum + 1024);
  unsigned char* A4g = A4a + (size_t)tc * B * K3B;
  float* INCa  = (float*)(A4g + (size_t)tc * B * K3B);
  float* INCg  = INCa + (size_t)tc * NEURONS;
  float* state = INCg + (size_t)tc * NEURONS;

  build_wt<<<256, 256, 0, stream>>>(WA, WG, WTa, WTg);
  colsum_w<<<4, 256, 0, stream>>>(WA, WG, colsum);

  const int nwpi = tc * 256;              // split waves per input
  const int splitBlocks = nwpi / 2;       // 2 inputs, 4 waves/block
  const int nm = tc * B / 128;            // 128-row m-tiles
  const int nwg = nm * 8;                 // x4 n-tiles x2 z
  const int nch = TT / tc;
  for (int c = 0; c < nch; ++c) {
    const size_t inOff = (size_t)c * tc * B * NIN;
    split3<<<splitBlocks, 256, 0, stream>>>(XA + inOff, XG + inOff, A4a, A4g, nwpi);
    gemm_i8_v10<<<nwg, 256, 0, stream>>>(A4a, A4g, WTa, WTg, colsum, INCa, INCg, nwg);
    neuron_scan<<<NEURONS / 256, 256, 0, stream>>>(
        INCa, INCg, S + (size_t)c * tc * NEURONS, state, tc, c == 0 ? 1 : 0);
  }
}